// Round 3
// baseline (773.231 us; speedup 1.0000x reference)
//
#include <hip/hip_runtime.h>
#include <math.h>

// Problem constants (from reference)
#define NB   4
#define NC   4
#define NF   257
#define NFRM 2000
#define PLANE (NB*NC*NF*NFRM)   // 8,224,000
#define EPS  1e-3f
#define INV_FN (1.0f/514000.0f) // 1/(NF*NFRM)

#define RFC  29                 // k_r frequency chunks
#define RFP  9                  // f per chunk (29*9=261 >= 257)
#define UT   256                // k_u threads
#define UK   8                  // contiguous frames per thread (250*8 = 2000)

__device__ __forceinline__ float2 cmulf(float2 a, float2 b) {
  return make_float2(a.x*b.x - a.y*b.y, a.x*b.y + a.y*b.x);
}

// zero rsum (32000) + gpart (48)
__global__ __launch_bounds__(256)
void k_zero(float* __restrict__ rsum, float* __restrict__ gpart) {
  int idx = blockIdx.x*256 + threadIdx.x;
  if (idx < 32000) rsum[idx] = 0.f;
  else if (idx < 32048) gpart[idx-32000] = 0.f;
}

// r-pass: rsum[b,c,n] += sum over f-chunk of |X|^2 (atomic), gpart[bc] += total
__global__ __launch_bounds__(256)
void k_r(const float* __restrict__ Xr, const float* __restrict__ Xi,
         float* __restrict__ rsum, float* __restrict__ gpart)
{
  const int tid = threadIdx.x;
  const int q   = blockIdx.x*256 + tid;   // float4 index over n, 500 valid
  const int fc  = blockIdx.y;
  const int bc  = blockIdx.z;
  float4 s4 = make_float4(0.f,0.f,0.f,0.f);
  if (q < 500) {
    const int f0 = fc*RFP;
    const int f1 = (f0+RFP < NF) ? (f0+RFP) : NF;
    const float4* r4 = (const float4*)(Xr + (size_t)(bc*NF+f0)*NFRM) + q;
    const float4* i4 = (const float4*)(Xi + (size_t)(bc*NF+f0)*NFRM) + q;
    for (int f=f0; f<f1; ++f) {
      float4 a = *r4, b2 = *i4;
      s4.x += a.x*a.x + b2.x*b2.x;
      s4.y += a.y*a.y + b2.y*b2.y;
      s4.z += a.z*a.z + b2.z*b2.z;
      s4.w += a.w*a.w + b2.w*b2.w;
      r4 += 500; i4 += 500;
    }
    float* rp = rsum + bc*NFRM + q*4;
    atomicAdd(rp+0, s4.x); atomicAdd(rp+1, s4.y);
    atomicAdd(rp+2, s4.z); atomicAdd(rp+3, s4.w);
  }
  float t = s4.x+s4.y+s4.z+s4.w;
  #pragma unroll
  for (int o=32;o;o>>=1) t += __shfl_down(t, o);
  __shared__ float wred[4];
  if ((tid & 63) == 0) wred[tid>>6] = t;
  __syncthreads();
  if (tid == 0) atomicAdd(&gpart[bc], wred[0]+wred[1]+wred[2]+wred[3]);
}

// weights kernel: w0g[b,c,n] = g[b,c] / max(2*sqrt(rsum), 1e-5); re-zero rsum
__global__ __launch_bounds__(256)
void k_w(float* __restrict__ rsum, const float* __restrict__ gpart,
         float* __restrict__ w0g)
{
  int idx = blockIdx.x*256 + threadIdx.x;   // 125*256 = 32000 exact
  int bc  = idx / NFRM;
  float g = fmaxf(gpart[bc]*INV_FN, EPS);
  float r = rsum[idx];
  w0g[idx] = g / fmaxf(2.0f*sqrtf(r), 1e-5f);
  rsum[idx] = 0.f;
}

// single-barrier 12-value block reduction, parity-double-buffered
#define REDUCE12(P)                                                       \
  {                                                                       \
    _Pragma("unroll")                                                     \
    for (int o=32;o;o>>=1) {                                              \
      _Pragma("unroll")                                                   \
      for (int i=0;i<12;i++) acc[i] += __shfl_down(acc[i], o);            \
    }                                                                     \
    if ((tid & 63) == 0) {                                                \
      const int wid = tid >> 6;                                           \
      _Pragma("unroll")                                                   \
      for (int i=0;i<12;i++) wpart[P][wid][i] = acc[i];                   \
    }                                                                     \
    __syncthreads();                                                      \
    _Pragma("unroll")                                                     \
    for (int i=0;i<12;i++) vsum[i] = 0.f;                                 \
    _Pragma("unroll")                                                     \
    for (int w=0;w<4;w++) {                                               \
      const float4* wp = (const float4*)wpart[P][w];                      \
      float4 p0 = wp[0], p1 = wp[1], p2 = wp[2];                          \
      vsum[0]+=p0.x; vsum[1]+=p0.y; vsum[2] +=p0.z; vsum[3] +=p0.w;       \
      vsum[4]+=p1.x; vsum[5]+=p1.y; vsum[6] +=p1.z; vsum[7] +=p1.w;       \
      vsum[8]+=p2.x; vsum[9]+=p2.y; vsum[10]+=p2.z; vsum[11]+=p2.w;       \
    }                                                                     \
  }

// Per-(b,f) update kernel. 256 threads, 8 CONTIGUOUS frames each.
template<bool FIRST, bool LAST>
__global__ __launch_bounds__(UT, 3)
void k_u(const float* Xsr, const float* Xsi,                 // current X source
         const float* __restrict__ Xor_, const float* __restrict__ Xoi_, // original (taps)
         float* Xdr, float* Xdi,                             // dest (may alias src)
         const float* __restrict__ w0gbuf,
         const float* __restrict__ gpart,
         float2* __restrict__ Wg)
{
  __shared__ __align__(16) float wpart[2][4][16];
  __shared__ float2 Wl[NC][NC];
  __shared__ float2 avec[NC];

  const int tid = threadIdx.x;
  const int f = blockIdx.x;
  const int b = blockIdx.y;
  const bool valid = tid < 250;
  const int n0 = tid*UK;                    // first frame owned
  const float norm = 1.0f/(float)NFRM;

  float igs[NC];
  #pragma unroll
  for (int c=0;c<NC;c++) {
    float g = fmaxf(gpart[b*NC+c]*INV_FN, EPS);
    igs[c] = 1.0f/sqrtf(g);
  }

  // load + rescale X (vectorized, contiguous frames)
  float2 x[NC][UK];
  #pragma unroll
  for (int c=0;c<NC;c++) {
    #pragma unroll
    for (int k=0;k<UK;k++) x[c][k] = make_float2(0.f,0.f);
    if (valid) {
      const size_t rb = ((size_t)(b*NC+c)*NF + f)*NFRM;
      float4 r0 = *(const float4*)(Xsr + rb + n0);
      float4 r1 = *(const float4*)(Xsr + rb + n0 + 4);
      float4 i0 = *(const float4*)(Xsi + rb + n0);
      float4 i1 = *(const float4*)(Xsi + rb + n0 + 4);
      float rr[8] = {r0.x,r0.y,r0.z,r0.w,r1.x,r1.y,r1.z,r1.w};
      float ii[8] = {i0.x,i0.y,i0.z,i0.w,i1.x,i1.y,i1.z,i1.w};
      #pragma unroll
      for (int k=0;k<UK;k++) x[c][k] = make_float2(rr[k]*igs[c], ii[k]*igs[c]);
    }
  }
  // precomputed weights
  float w0g[NC][UK];
  #pragma unroll
  for (int c=0;c<NC;c++) {
    #pragma unroll
    for (int k=0;k<UK;k++) w0g[c][k] = 0.f;
    if (valid) {
      const float* wb = w0gbuf + (b*NC+c)*NFRM + n0;
      float4 w0 = *(const float4*)(wb);
      float4 w1 = *(const float4*)(wb+4);
      float ww[8] = {w0.x,w0.y,w0.z,w0.w,w1.x,w1.y,w1.z,w1.w};
      #pragma unroll
      for (int k=0;k<UK;k++) w0g[c][k] = ww[k];
    }
  }
  // W load/init + rescale (wave 0 only)
  if (tid < 16) {
    const int c = tid>>2, d = tid&3;
    float2 w;
    if (FIRST) w = make_float2((c==d)?1.f:0.f, 0.f);
    else       w = Wg[(size_t)(b*NF+f)*16 + tid];
    Wl[c][d] = make_float2(w.x*igs[c], w.y*igs[c]);
  }

  // ---------- type-1 sweeps ----------
  #pragma unroll
  for (int s=0;s<NC;s++) {
    float acc[12];
    #pragma unroll
    for (int i=0;i<12;i++) acc[i] = 0.f;
    #pragma unroll
    for (int k=0;k<UK;k++) {
      float2 xs = x[s][k];
      float m = xs.x*xs.x + xs.y*xs.y;
      #pragma unroll
      for (int c=0;c<NC;c++) {
        float2 xc = x[c][k];
        float w = w0g[c][k];
        acc[c]   += w*(xc.x*xs.x + xc.y*xs.y);
        acc[4+c] += w*(xc.y*xs.x - xc.x*xs.y);
        acc[8+c] += w*m;
      }
    }
    float vsum[12];
    REDUCE12(s&1);
    float2 v[NC];
    #pragma unroll
    for (int c=0;c<NC;c++) {
      float dn = fmaxf(vsum[8+c]*norm, EPS);
      v[c] = make_float2(vsum[c]*norm/dn, vsum[4+c]*norm/dn);
    }
    v[s] = make_float2(1.0f - 1.0f/sqrtf(fmaxf(vsum[8+s]*norm, EPS)), 0.f);
    #pragma unroll
    for (int k=0;k<UK;k++) {
      float2 xs = x[s][k];
      #pragma unroll
      for (int c=0;c<NC;c++) {
        float2 xv = x[c][k];
        xv.x -= v[c].x*xs.x - v[c].y*xs.y;
        xv.y -= v[c].x*xs.y + v[c].y*xs.x;
        x[c][k] = xv;
      }
    }
    if (tid < 16) {
      const int c = tid>>2, d = tid&3;
      float2 wsd = Wl[s][d];
      float2 wv = Wl[c][d];
      wv.x -= v[c].x*wsd.x - v[c].y*wsd.y;
      wv.y -= v[c].x*wsd.y + v[c].y*wsd.x;
      Wl[c][d] = wv;
    }
  }

  // ---------- type-2 sweeps ----------
  #pragma unroll
  for (int s=0;s<NC;s++) {
    const size_t ob = ((size_t)(b*NC+s)*NF + f)*NFRM;
    // aligned 12-float window [n0-4, n0+8) of the tap plane, shared by both taps
    float f12r[12], f12i[12];
    {
      float4 r0=make_float4(0,0,0,0), r1=r0, r2=r0, i0=r0, i1=r0, i2=r0;
      if (valid) {
        const float* tp = Xor_ + ob + n0 - 4;
        const float* ti = Xoi_ + ob + n0 - 4;
        if (tid > 0) { r0 = *(const float4*)tp; i0 = *(const float4*)ti; }
        r1 = *(const float4*)(tp+4);  i1 = *(const float4*)(ti+4);
        r2 = *(const float4*)(tp+8);  i2 = *(const float4*)(ti+8);
      }
      float tr[12] = {r0.x,r0.y,r0.z,r0.w,r1.x,r1.y,r1.z,r1.w,r2.x,r2.y,r2.z,r2.w};
      float tii[12]= {i0.x,i0.y,i0.z,i0.w,i1.x,i1.y,i1.z,i1.w,i2.x,i2.y,i2.z,i2.w};
      #pragma unroll
      for (int j=0;j<12;j++) { f12r[j]=tr[j]; f12i[j]=tii[j]; }
    }
    #pragma unroll
    for (int t2=0;t2<2;t2++) {
      float acc[12];
      #pragma unroll
      for (int i=0;i<12;i++) acc[i] = 0.f;
      #pragma unroll
      for (int k=0;k<UK;k++) {
        float2 xs = make_float2(f12r[k+1+t2], f12i[k+1+t2]);  // frame n0+k+t2-3
        float m = xs.x*xs.x + xs.y*xs.y;
        #pragma unroll
        for (int c=0;c<NC;c++) {
          float2 xc = x[c][k];
          float w = w0g[c][k];
          acc[c]   += w*(xc.x*xs.x + xc.y*xs.y);
          acc[4+c] += w*(xc.y*xs.x - xc.x*xs.y);
          acc[8+c] += w*m;
        }
      }
      float vsum[12];
      REDUCE12((s*2+t2)&1);   // parity continues alternating (type-1 ended on 1)
      float2 v[NC];
      #pragma unroll
      for (int c=0;c<NC;c++) {
        float dn = fmaxf(vsum[8+c]*norm, EPS);
        v[c] = make_float2(vsum[c]*norm/dn, vsum[4+c]*norm/dn);
      }
      #pragma unroll
      for (int k=0;k<UK;k++) {
        float2 xs = make_float2(f12r[k+1+t2], f12i[k+1+t2]);
        #pragma unroll
        for (int c=0;c<NC;c++) {
          float2 xv = x[c][k];
          xv.x -= v[c].x*xs.x - v[c].y*xs.y;
          xv.y -= v[c].x*xs.y + v[c].y*xs.x;
          x[c][k] = xv;
        }
      }
    }
  }

  // ---------- epilogue ----------
  if (LAST) {
    if (tid == 0) {
      float2 A[4][4], bb[4], xv[4];
      for (int i=0;i<4;i++)
        for (int j=0;j<4;j++)
          A[i][j] = Wl[j][i];
      for (int i=0;i<4;i++) A[i][i].x += 1e-6f;
      bb[0] = make_float2(1.f,0.f);
      bb[1] = make_float2(0.f,0.f);
      bb[2] = make_float2(0.f,0.f);
      bb[3] = make_float2(0.f,0.f);
      for (int col=0; col<4; ++col) {
        int p = col;
        float best = A[col][col].x*A[col][col].x + A[col][col].y*A[col][col].y;
        for (int r=col+1;r<4;r++) {
          float m = A[r][col].x*A[r][col].x + A[r][col].y*A[r][col].y;
          if (m > best) { best = m; p = r; }
        }
        if (p != col) {
          for (int j=0;j<4;j++) { float2 ts = A[col][j]; A[col][j] = A[p][j]; A[p][j] = ts; }
          float2 ts = bb[col]; bb[col] = bb[p]; bb[p] = ts;
        }
        float2 piv = A[col][col];
        float ib = 1.0f / (piv.x*piv.x + piv.y*piv.y);
        float2 inv = make_float2(piv.x*ib, -piv.y*ib);
        for (int r=col+1;r<4;r++) {
          float2 fac = cmulf(A[r][col], inv);
          for (int j=col;j<4;j++) {
            float2 pr = cmulf(fac, A[col][j]);
            A[r][j].x -= pr.x; A[r][j].y -= pr.y;
          }
          float2 pb = cmulf(fac, bb[col]);
          bb[r].x -= pb.x; bb[r].y -= pb.y;
        }
      }
      for (int r=3;r>=0;r--) {
        float2 t = bb[r];
        for (int j=r+1;j<4;j++) {
          float2 pr = cmulf(A[r][j], xv[j]);
          t.x -= pr.x; t.y -= pr.y;
        }
        float2 d = A[r][r];
        float ib = 1.0f/(d.x*d.x + d.y*d.y);
        xv[r] = cmulf(t, make_float2(d.x*ib, -d.y*ib));
      }
      for (int c=0;c<4;c++) avec[c] = xv[c];
    }
    __syncthreads();
    if (valid) {
      #pragma unroll
      for (int c=0;c<NC;c++) {
        const size_t rb = ((size_t)(b*NC+c)*NF + f)*NFRM;
        float2 a = avec[c];
        float2 y[UK];
        #pragma unroll
        for (int k=0;k<UK;k++) y[k] = cmulf(a, x[c][k]);
        float4 o0 = make_float4(y[0].x,y[1].x,y[2].x,y[3].x);
        float4 o1 = make_float4(y[4].x,y[5].x,y[6].x,y[7].x);
        float4 o2 = make_float4(y[0].y,y[1].y,y[2].y,y[3].y);
        float4 o3 = make_float4(y[4].y,y[5].y,y[6].y,y[7].y);
        *(float4*)(Xdr + rb + n0)     = o0;
        *(float4*)(Xdr + rb + n0 + 4) = o1;
        *(float4*)(Xdi + rb + n0)     = o2;
        *(float4*)(Xdi + rb + n0 + 4) = o3;
      }
    }
  } else {
    if (valid) {
      #pragma unroll
      for (int c=0;c<NC;c++) {
        const size_t rb = ((size_t)(b*NC+c)*NF + f)*NFRM;
        float4 o0 = make_float4(x[c][0].x,x[c][1].x,x[c][2].x,x[c][3].x);
        float4 o1 = make_float4(x[c][4].x,x[c][5].x,x[c][6].x,x[c][7].x);
        float4 o2 = make_float4(x[c][0].y,x[c][1].y,x[c][2].y,x[c][3].y);
        float4 o3 = make_float4(x[c][4].y,x[c][5].y,x[c][6].y,x[c][7].y);
        *(float4*)(Xdr + rb + n0)     = o0;
        *(float4*)(Xdr + rb + n0 + 4) = o1;
        *(float4*)(Xdi + rb + n0)     = o2;
        *(float4*)(Xdi + rb + n0 + 4) = o3;
      }
    }
    if (tid < 16) Wg[(size_t)(b*NF+f)*16 + tid] = Wl[tid>>2][tid&3];
  }
}

extern "C" void kernel_launch(void* const* d_in, const int* in_sizes, int n_in,
                              void* d_out, int out_size, void* d_ws, size_t ws_size,
                              hipStream_t stream)
{
  (void)in_sizes; (void)n_in; (void)out_size; (void)ws_size;
  const float* xr_in = (const float*)d_in[0];
  const float* xi_in = (const float*)d_in[1];
  float* outr = (float*)d_out;
  float* outi = outr + PLANE;

  char*  ws    = (char*)d_ws;
  float* rsum  = (float*)ws;                       // 32000 floats = 128 KB
  float* w0g   = (float*)(ws + 128000);            // 32000 floats = 128 KB
  float* gpart = (float*)(ws + 256000);            // 48 floats
  float2* Wg   = (float2*)(ws + 256000 + 256);     // 1028*16 float2 = 131,584 B

  dim3 grR(2, RFC, NB*NC);    // 928 blocks
  dim3 grU(NF, NB);           // 1028 blocks

  k_zero<<<126, 256, 0, stream>>>(rsum, gpart);

  // iteration 0 (X = original input)
  k_r<<<grR, 256, 0, stream>>>(xr_in, xi_in, rsum, gpart + 0);
  k_w<<<125, 256, 0, stream>>>(rsum, gpart + 0, w0g);
  k_u<true,false><<<grU, UT, 0, stream>>>(xr_in, xi_in, xr_in, xi_in,
                                          outr, outi, w0g, gpart + 0, Wg);
  // iteration 1
  k_r<<<grR, 256, 0, stream>>>(outr, outi, rsum, gpart + 16);
  k_w<<<125, 256, 0, stream>>>(rsum, gpart + 16, w0g);
  k_u<false,false><<<grU, UT, 0, stream>>>(outr, outi, xr_in, xi_in,
                                           outr, outi, w0g, gpart + 16, Wg);
  // iteration 2 + projection_back
  k_r<<<grR, 256, 0, stream>>>(outr, outi, rsum, gpart + 32);
  k_w<<<125, 256, 0, stream>>>(rsum, gpart + 32, w0g);
  k_u<false,true><<<grU, UT, 0, stream>>>(outr, outi, xr_in, xi_in,
                                          outr, outi, w0g, gpart + 32, Wg);
}